// Round 1
// baseline (540.677 us; speedup 1.0000x reference)
//
#include <hip/hip_runtime.h>
#include <hip/hip_bf16.h>

typedef __hip_bfloat16 bf16;
typedef __attribute__((ext_vector_type(8))) __bf16 bf16x8;
typedef __attribute__((ext_vector_type(4))) float f32x4;

typedef const __attribute__((address_space(1))) void cgvoid;
typedef __attribute__((address_space(3))) void lvoid;

__device__ __forceinline__ float ldf(const float* p){ return *p; }
__device__ __forceinline__ float ldf(const bf16* p){ return __bfloat162float(*p); }

constexpr int B_ = 256, S_ = 10, D_ = 4096, W_ = 5, C_ = 6;
constexpr int K_ = D_ * W_;      // 20480
constexpr int M_ = 256, N_ = 4096;
constexpr int KS_ = 8;           // split-K factor
constexpr int KPER = K_ / KS_;   // 2560
constexpr int BK_ = 32;
constexpr int ITERS = KPER / BK_; // 80

// ---------------- dtype detection ----------------
// If the float tensors are actually fp32, reading them as bf16 makes ~half the
// elements (low mantissa halves) have garbage exponents. True bf16 N(0,1) data
// is ~100% "sane". Writes flag=1 (bf16) or 0 (fp32) into ws.
__global__ void detect_kernel(const unsigned short* __restrict__ xr, int* __restrict__ flag){
    int lane = threadIdx.x;
    int sane = 0;
    for (int i = lane; i < 2048; i += 64){
        unsigned short u = xr[i];
        int e = (u >> 7) & 0xFF;
        if ((e >= 97 && e <= 137) || ((u & 0x7FFF) == 0)) sane++;
    }
    #pragma unroll
    for (int off = 32; off > 0; off >>= 1) sane += __shfl_down(sane, off);
    if (lane == 0) *flag = (sane >= 1536) ? 1 : 0;  // >=75% sane -> bf16
}

// ---------------- cosine weights ----------------
// w[b,s] = <x[b,s], x[b,6]> / (max(||x[b,s]||,eps)*max(||x[b,6]||,eps))
template<typename T>
__global__ __launch_bounds__(256) void weights_kernel(const T* __restrict__ x,
                                                      float* __restrict__ wbuf,
                                                      const int* __restrict__ flag, int want){
    if (*flag != want) return;
    int b = blockIdx.x, tid = threadIdx.x;
    const T* xb = x + (size_t)b * S_ * D_;
    float dot[S_], nr[S_];
    #pragma unroll
    for (int s = 0; s < S_; ++s){ dot[s] = 0.f; nr[s] = 0.f; }
    for (int i = tid; i < D_; i += 256){
        float xc = ldf(xb + C_*D_ + i);
        #pragma unroll
        for (int s = 0; s < S_; ++s){
            float v = ldf(xb + s*D_ + i);
            dot[s] += v * xc;
            nr[s]  += v * v;
        }
    }
    int lane = tid & 63, wv = tid >> 6;
    #pragma unroll
    for (int s = 0; s < S_; ++s){
        #pragma unroll
        for (int off = 32; off > 0; off >>= 1){
            dot[s] += __shfl_down(dot[s], off);
            nr[s]  += __shfl_down(nr[s], off);
        }
    }
    __shared__ float sd[4][S_], sn[4][S_];
    if (lane == 0){
        #pragma unroll
        for (int s = 0; s < S_; ++s){ sd[wv][s] = dot[s]; sn[wv][s] = nr[s]; }
    }
    __syncthreads();
    if (tid < S_){
        float Dv = 0.f, Nv = 0.f;
        #pragma unroll
        for (int w2 = 0; w2 < 4; ++w2){ Dv += sd[w2][tid]; Nv += sn[w2][tid]; }
        sd[0][tid] = Dv; sn[0][tid] = sqrtf(Nv);
    }
    __syncthreads();
    if (tid < S_){
        float cn = sn[0][C_];
        float wv2 = sd[0][tid] / (fmaxf(sn[0][tid], 1e-8f) * fmaxf(cn, 1e-8f));
        wbuf[b*S_ + tid] = wv2;
    }
}

// ---------------- Z2 build ----------------
// Z2[b, i*5+k] = sum_{t=0..5} x[b,t+k,i]*w[b,t+k]   (bf16 store, fp32 accum)
template<typename T>
__global__ __launch_bounds__(256) void z_kernel(const T* __restrict__ x,
                                                const float* __restrict__ wbuf,
                                                bf16* __restrict__ Z,
                                                const int* __restrict__ flag, int want){
    if (*flag != want) return;
    int tid = threadIdx.x;
    int gid = blockIdx.x * 256 + tid;        // 256*4096 threads
    int b = gid >> 12, i = gid & (D_ - 1);
    __shared__ float wsh[S_];
    if (tid < S_) wsh[tid] = wbuf[b*S_ + tid];
    __syncthreads();
    const T* xb = x + (size_t)b * S_ * D_ + i;
    float v[S_];
    #pragma unroll
    for (int s = 0; s < S_; ++s) v[s] = ldf(xb + s*D_) * wsh[s];
    bf16* zp = Z + (size_t)b * K_ + i * W_;
    #pragma unroll
    for (int k = 0; k < W_; ++k){
        float acc = 0.f;
        #pragma unroll
        for (int t = 0; t < 6; ++t) acc += v[k + t];
        zp[k] = __float2bfloat16(acc);
    }
}

// ---------------- GEMM: P[ks] += A(Z2) * conv_w^T ----------------
// MODE=1: conv_w is bf16 (global_load_lds staging for both operands)
// MODE=0: conv_w is fp32 (float4 load + in-register bf16 cvt for B)
template<int MODE>
__global__ __launch_bounds__(256, 2) void gemm_kernel(const void* __restrict__ Wv,
                                                      const bf16* __restrict__ A,
                                                      float* __restrict__ P,
                                                      const int* __restrict__ flag){
    if (*flag != MODE) return;
    constexpr int SB = MODE ? BK_ : (BK_ + 8);   // fp32 path pads LDS stride (40) to break conflicts
    __shared__ alignas(16) __bf16 As[128 * BK_];
    __shared__ alignas(16) __bf16 Bs[128 * SB];
    int tid = threadIdx.x;
    int bid = blockIdx.x;
    int mt = bid & 1, nt = (bid >> 1) & 31, ks = bid >> 6;
    int lane = tid & 63, wv = tid >> 6;
    int wm = wv & 1, wn = wv >> 1;
    int r16 = lane & 15, quad = lane >> 4;

    const __bf16* Ab = (const __bf16*)A + (size_t)mt * 128 * K_ + (size_t)ks * KPER;

    f32x4 acc[4][4];
    #pragma unroll
    for (int fm = 0; fm < 4; ++fm)
        #pragma unroll
        for (int fn = 0; fn < 4; ++fn) acc[fm][fn] = (f32x4){0.f, 0.f, 0.f, 0.f};

    for (int kk = 0; kk < ITERS; ++kk){
        int k0 = kk * BK_;
        __syncthreads();
        // stage A tile 128x32 bf16 via async global->LDS, width 16
        #pragma unroll
        for (int r = 0; r < 2; ++r){
            int c = r * 256 + tid;
            const __bf16* src = Ab + (size_t)(c >> 2) * K_ + (c & 3) * 8 + k0;
            __builtin_amdgcn_global_load_lds((cgvoid*)src, (lvoid*)(As + c * 8), 16, 0, 0);
        }
        if constexpr (MODE == 1){
            const __bf16* Bb = (const __bf16*)Wv + (size_t)nt * 128 * K_ + (size_t)ks * KPER;
            #pragma unroll
            for (int r = 0; r < 2; ++r){
                int c = r * 256 + tid;
                const __bf16* src = Bb + (size_t)(c >> 2) * K_ + (c & 3) * 8 + k0;
                __builtin_amdgcn_global_load_lds((cgvoid*)src, (lvoid*)(Bs + c * 8), 16, 0, 0);
            }
        } else {
            const float* Bb = (const float*)Wv + (size_t)nt * 128 * K_ + (size_t)ks * KPER;
            #pragma unroll
            for (int r = 0; r < 2; ++r){
                int pc = r * 256 + tid;
                const float* src = Bb + (size_t)(pc >> 2) * K_ + (pc & 3) * 8 + k0;
                float4 f0 = *(const float4*)src;
                float4 f1 = *(const float4*)(src + 4);
                bf16x8 u;
                u[0] = (__bf16)f0.x; u[1] = (__bf16)f0.y; u[2] = (__bf16)f0.z; u[3] = (__bf16)f0.w;
                u[4] = (__bf16)f1.x; u[5] = (__bf16)f1.y; u[6] = (__bf16)f1.z; u[7] = (__bf16)f1.w;
                *(bf16x8*)(Bs + (pc >> 2) * SB + (pc & 3) * 8) = u;
            }
        }
        __syncthreads();
        bf16x8 af[4], bfr[4];
        #pragma unroll
        for (int fm = 0; fm < 4; ++fm)
            af[fm] = *(const bf16x8*)(As + (wm * 64 + fm * 16 + r16) * BK_ + quad * 8);
        #pragma unroll
        for (int fn = 0; fn < 4; ++fn)
            bfr[fn] = *(const bf16x8*)(Bs + (wn * 64 + fn * 16 + r16) * SB + quad * 8);
        #pragma unroll
        for (int fm = 0; fm < 4; ++fm)
            #pragma unroll
            for (int fn = 0; fn < 4; ++fn)
                acc[fm][fn] = __builtin_amdgcn_mfma_f32_16x16x32_bf16(af[fm], bfr[fn], acc[fm][fn], 0, 0, 0);
    }

    // epilogue: write fp32 partials. C/D layout: col=lane&15 (N), row=quad*4+reg (M)
    float* Pb = P + (size_t)ks * M_ * N_;
    #pragma unroll
    for (int fm = 0; fm < 4; ++fm){
        #pragma unroll
        for (int fn = 0; fn < 4; ++fn){
            int n = nt * 128 + wn * 64 + fn * 16 + r16;
            #pragma unroll
            for (int r = 0; r < 4; ++r){
                int m = mt * 128 + wm * 64 + fm * 16 + quad * 4 + r;
                Pb[(size_t)m * N_ + n] = acc[fm][fn][r];
            }
        }
    }
}

// ---------------- split-K reduce + bias + mean scale ----------------
template<typename T>
__global__ __launch_bounds__(256) void reduce_kernel(const float* __restrict__ P,
                                                     const T* __restrict__ bias,
                                                     void* __restrict__ out,
                                                     const int* __restrict__ flag, int want){
    if (*flag != want) return;
    int gid = blockIdx.x * 256 + threadIdx.x;   // 262144 float4 groups
    int o4 = gid * 4;
    int n = o4 & (N_ - 1);
    float4 s = make_float4(0.f, 0.f, 0.f, 0.f);
    #pragma unroll
    for (int k2 = 0; k2 < KS_; ++k2){
        float4 p = *(const float4*)(P + (size_t)k2 * M_ * N_ + o4);
        s.x += p.x; s.y += p.y; s.z += p.z; s.w += p.w;
    }
    const float inv6 = 1.f / 6.f;
    float r0 = s.x * inv6 + ldf(bias + n);
    float r1 = s.y * inv6 + ldf(bias + n + 1);
    float r2 = s.z * inv6 + ldf(bias + n + 2);
    float r3 = s.w * inv6 + ldf(bias + n + 3);
    if constexpr (sizeof(T) == 2){
        bf16 h0 = __float2bfloat16(r0), h1 = __float2bfloat16(r1);
        bf16 h2 = __float2bfloat16(r2), h3 = __float2bfloat16(r3);
        ushort4 o;
        o.x = *(unsigned short*)&h0; o.y = *(unsigned short*)&h1;
        o.z = *(unsigned short*)&h2; o.w = *(unsigned short*)&h3;
        *(ushort4*)((unsigned short*)out + o4) = o;
    } else {
        *(float4*)((float*)out + o4) = make_float4(r0, r1, r2, r3);
    }
}

extern "C" void kernel_launch(void* const* d_in, const int* in_sizes, int n_in,
                              void* d_out, int out_size, void* d_ws, size_t ws_size,
                              hipStream_t stream){
    const void* x      = d_in[0];
    const void* conv_w = d_in[1];
    const void* conv_b = d_in[2];

    char* ws   = (char*)d_ws;
    int*  flag = (int*)ws;                               // 4 B
    float* wbuf = (float*)(ws + 1024);                   // 2560 floats
    bf16*  Z    = (bf16*)(ws + 16384);                   // 256*20480 bf16 = 10,485,760 B
    float* P    = (float*)(ws + 10502144);               // 8*256*4096 fp32 = 33,554,432 B (end ~44 MB)

    detect_kernel<<<1, 64, 0, stream>>>((const unsigned short*)x, flag);

    weights_kernel<bf16 ><<<256, 256, 0, stream>>>((const bf16*)x,  wbuf, flag, 1);
    weights_kernel<float><<<256, 256, 0, stream>>>((const float*)x, wbuf, flag, 0);

    z_kernel<bf16 ><<<4096, 256, 0, stream>>>((const bf16*)x,  wbuf, Z, flag, 1);
    z_kernel<float><<<4096, 256, 0, stream>>>((const float*)x, wbuf, Z, flag, 0);

    gemm_kernel<1><<<512, 256, 0, stream>>>(conv_w, Z, P, flag);
    gemm_kernel<0><<<512, 256, 0, stream>>>(conv_w, Z, P, flag);

    reduce_kernel<bf16 ><<<1024, 256, 0, stream>>>(P, (const bf16*)conv_b,  d_out, flag, 1);
    reduce_kernel<float><<<1024, 256, 0, stream>>>(P, (const float*)conv_b, d_out, flag, 0);
}

// Round 2
// 522.842 us; speedup vs baseline: 1.0341x; 1.0341x over previous
//
#include <hip/hip_runtime.h>
#include <hip/hip_bf16.h>

typedef __hip_bfloat16 bf16;
typedef __attribute__((ext_vector_type(8))) __bf16 bf16x8;
typedef __attribute__((ext_vector_type(4))) float f32x4;

typedef const __attribute__((address_space(1))) void cgvoid;
typedef __attribute__((address_space(3))) void lvoid;

constexpr int B_ = 256, S_ = 10, D_ = 4096, W_ = 5;
constexpr int K_ = D_ * W_;       // 20480
constexpr int M_ = 256, N_ = 4096;
constexpr int KS_ = 8;            // split-K factor
constexpr int KPER = K_ / KS_;    // 2560
constexpr int BK_ = 32;
constexpr int ITERS = KPER / BK_; // 80
constexpr float EPSV = 1e-8f;

// ---------------- dtype detection (1 block, ~3us insurance) ----------------
// fp32 data read as bf16 shorts: ~half the halves have garbage exponents.
// true bf16 N(0,1): ~100% sane. flag=1 -> bf16, flag=0 -> fp32.
__global__ void detect_kernel(const unsigned short* __restrict__ xr, int* __restrict__ flag){
    int lane = threadIdx.x;
    int sane = 0;
    for (int i = lane; i < 2048; i += 64){
        unsigned short u = xr[i];
        int e = (u >> 7) & 0xFF;
        if ((e >= 97 && e <= 137) || ((u & 0x7FFF) == 0)) sane++;
    }
    #pragma unroll
    for (int off = 32; off > 0; off >>= 1) sane += __shfl_down(sane, off);
    if (lane == 0) *flag = (sane >= 1536) ? 1 : 0;
}

// ---------------- fused cosine-weights + Z build ----------------
// One block per batch b. 512 threads, 8 consecutive i's per thread, x kept in
// registers (bf16->f32), block-reduce dots/norms, then window-sums -> Z (bf16).
// Z[b, i*5+k] = sum_{t=0..5} x[b,t+k,i] * w[b,t+k]
__global__ __launch_bounds__(512) void zw_kernel(const void* __restrict__ xv,
                                                 bf16* __restrict__ Z,
                                                 const int* __restrict__ flag){
    const bool isb = (*flag != 0);
    int b = blockIdx.x, t = threadIdx.x;
    int i0 = t * 8;
    float f[S_][8];
    if (isb){
        const __bf16* xb = (const __bf16*)xv + (size_t)b * S_ * D_ + i0;
        #pragma unroll
        for (int s = 0; s < S_; ++s){
            bf16x8 v = *(const bf16x8*)(xb + s * D_);
            #pragma unroll
            for (int j = 0; j < 8; ++j) f[s][j] = (float)v[j];
        }
    } else {
        const float* xb = (const float*)xv + (size_t)b * S_ * D_ + i0;
        #pragma unroll
        for (int s = 0; s < S_; ++s){
            float4 a = *(const float4*)(xb + s * D_);
            float4 c = *(const float4*)(xb + s * D_ + 4);
            f[s][0]=a.x; f[s][1]=a.y; f[s][2]=a.z; f[s][3]=a.w;
            f[s][4]=c.x; f[s][5]=c.y; f[s][6]=c.z; f[s][7]=c.w;
        }
    }
    float dsum[S_], nsum[S_];
    #pragma unroll
    for (int s = 0; s < S_; ++s){
        float d = 0.f, n = 0.f;
        #pragma unroll
        for (int j = 0; j < 8; ++j){ d += f[s][j] * f[6][j]; n += f[s][j] * f[s][j]; }
        dsum[s] = d; nsum[s] = n;
    }
    int lane = t & 63, wv = t >> 6;
    #pragma unroll
    for (int s = 0; s < S_; ++s){
        #pragma unroll
        for (int off = 32; off > 0; off >>= 1){
            dsum[s] += __shfl_down(dsum[s], off);
            nsum[s] += __shfl_down(nsum[s], off);
        }
    }
    __shared__ float sd[8][S_], sn[8][S_], wsh[S_];
    if (lane == 0){
        #pragma unroll
        for (int s = 0; s < S_; ++s){ sd[wv][s] = dsum[s]; sn[wv][s] = nsum[s]; }
    }
    __syncthreads();
    if (t < S_){
        float Dv = 0.f, Nv = 0.f;
        #pragma unroll
        for (int w2 = 0; w2 < 8; ++w2){ Dv += sd[w2][t]; Nv += sn[w2][t]; }
        sd[0][t] = Dv; sn[0][t] = sqrtf(Nv);
    }
    __syncthreads();
    if (t < S_){
        wsh[t] = sd[0][t] / (fmaxf(sn[0][t], EPSV) * fmaxf(sn[0][6], EPSV));
    }
    __syncthreads();
    float w_[S_];
    #pragma unroll
    for (int s = 0; s < S_; ++s) w_[s] = wsh[s];
    alignas(16) __bf16 zout[40];
    #pragma unroll
    for (int k = 0; k < W_; ++k){
        #pragma unroll
        for (int j = 0; j < 8; ++j){
            float acc = 0.f;
            #pragma unroll
            for (int t2 = 0; t2 < 6; ++t2) acc += w_[k + t2] * f[k + t2][j];
            zout[j * 5 + k] = (__bf16)acc;
        }
    }
    __bf16* zp = (__bf16*)Z + (size_t)b * K_ + (size_t)i0 * W_;   // 80B/thread, contiguous
    #pragma unroll
    for (int v = 0; v < 5; ++v) *(bf16x8*)(zp + v * 8) = *(const bf16x8*)(zout + v * 8);
}

// ---------------- GEMM: P[ks] = Z(256xK-slice) * conv_w^T(128 cols) ----------------
// Tile M=256(full) x N=128 x BK=32. 512 threads = 8 waves (4M x 2N).
// conv_w read exactly once across the grid. Z slice streamed from LLC.
__global__ __launch_bounds__(512, 2) void gemm_kernel(const void* __restrict__ Wv,
                                                      const bf16* __restrict__ A,
                                                      float* __restrict__ P,
                                                      const int* __restrict__ flag){
    __shared__ alignas(16) __bf16 As[256 * BK_];   // 16KB
    __shared__ alignas(16) __bf16 Bs[128 * BK_];   //  8KB
    const bool isb = (*flag != 0);
    int tid = threadIdx.x, bid = blockIdx.x;
    int nt = bid & 31, ks = bid >> 5;
    int lane = tid & 63, wv = tid >> 6;
    int wm = wv & 3, wn = wv >> 2;
    int r16 = lane & 15, quad = lane >> 4;

    const __bf16* Ab = (const __bf16*)A + (size_t)ks * KPER;

    f32x4 acc[4][4];
    #pragma unroll
    for (int fm = 0; fm < 4; ++fm)
        #pragma unroll
        for (int fn = 0; fn < 4; ++fn) acc[fm][fn] = (f32x4){0.f, 0.f, 0.f, 0.f};

    for (int kk = 0; kk < ITERS; ++kk){
        int k0 = kk * BK_;
        __syncthreads();
        #pragma unroll
        for (int r = 0; r < 2; ++r){
            int c = r * 512 + tid;                      // 1024 x 16B = 256 rows x 32
            const __bf16* src = Ab + (size_t)(c >> 2) * K_ + (c & 3) * 8 + k0;
            __builtin_amdgcn_global_load_lds((cgvoid*)src, (lvoid*)(As + c * 8), 16, 0, 0);
        }
        if (isb){
            const __bf16* Bb = (const __bf16*)Wv + (size_t)(nt * 128) * K_ + (size_t)ks * KPER;
            const __bf16* src = Bb + (size_t)(tid >> 2) * K_ + (tid & 3) * 8 + k0;
            __builtin_amdgcn_global_load_lds((cgvoid*)src, (lvoid*)(Bs + tid * 8), 16, 0, 0);
        } else {
            const float* Bb = (const float*)Wv + (size_t)(nt * 128) * K_ + (size_t)ks * KPER;
            const float* src = Bb + (size_t)(tid >> 2) * K_ + (tid & 3) * 8 + k0;
            float4 f0 = *(const float4*)src;
            float4 f1 = *(const float4*)(src + 4);
            bf16x8 u;
            u[0] = (__bf16)f0.x; u[1] = (__bf16)f0.y; u[2] = (__bf16)f0.z; u[3] = (__bf16)f0.w;
            u[4] = (__bf16)f1.x; u[5] = (__bf16)f1.y; u[6] = (__bf16)f1.z; u[7] = (__bf16)f1.w;
            *(bf16x8*)(Bs + (tid >> 2) * BK_ + (tid & 3) * 8) = u;
        }
        __syncthreads();
        bf16x8 af[4], bfr[4];
        #pragma unroll
        for (int fm = 0; fm < 4; ++fm)
            af[fm] = *(const bf16x8*)(As + (wm * 64 + fm * 16 + r16) * BK_ + quad * 8);
        #pragma unroll
        for (int fn = 0; fn < 4; ++fn)
            bfr[fn] = *(const bf16x8*)(Bs + (wn * 64 + fn * 16 + r16) * BK_ + quad * 8);
        #pragma unroll
        for (int fm = 0; fm < 4; ++fm)
            #pragma unroll
            for (int fn = 0; fn < 4; ++fn)
                acc[fm][fn] = __builtin_amdgcn_mfma_f32_16x16x32_bf16(af[fm], bfr[fn], acc[fm][fn], 0, 0, 0);
    }

    // C/D layout: col = lane&15 (N), row = quad*4 + reg (M)
    float* Pb = P + (size_t)ks * M_ * N_;
    #pragma unroll
    for (int fm = 0; fm < 4; ++fm){
        #pragma unroll
        for (int fn = 0; fn < 4; ++fn){
            int n = nt * 128 + wn * 64 + fn * 16 + r16;
            #pragma unroll
            for (int r = 0; r < 4; ++r){
                int m = wm * 64 + fm * 16 + quad * 4 + r;
                Pb[(size_t)m * N_ + n] = acc[fm][fn][r];
            }
        }
    }
}

// ---------------- split-K reduce + bias + mean scale ----------------
__global__ __launch_bounds__(256) void reduce_kernel(const float* __restrict__ P,
                                                     const void* __restrict__ bias,
                                                     void* __restrict__ out,
                                                     const int* __restrict__ flag){
    const bool isb = (*flag != 0);
    int gid = blockIdx.x * 256 + threadIdx.x;   // 262144 float4 groups
    int o4 = gid * 4;
    int n = o4 & (N_ - 1);
    float4 s = make_float4(0.f, 0.f, 0.f, 0.f);
    #pragma unroll
    for (int k2 = 0; k2 < KS_; ++k2){
        float4 p = *(const float4*)(P + (size_t)k2 * M_ * N_ + o4);
        s.x += p.x; s.y += p.y; s.z += p.z; s.w += p.w;
    }
    const float inv6 = 1.f / 6.f;
    float b0, b1, b2, b3;
    if (isb){
        const bf16* bp = (const bf16*)bias + n;
        b0 = __bfloat162float(bp[0]); b1 = __bfloat162float(bp[1]);
        b2 = __bfloat162float(bp[2]); b3 = __bfloat162float(bp[3]);
    } else {
        const float* bp = (const float*)bias + n;
        b0 = bp[0]; b1 = bp[1]; b2 = bp[2]; b3 = bp[3];
    }
    float r0 = s.x * inv6 + b0;
    float r1 = s.y * inv6 + b1;
    float r2 = s.z * inv6 + b2;
    float r3 = s.w * inv6 + b3;
    if (isb){
        bf16 h0 = __float2bfloat16(r0), h1 = __float2bfloat16(r1);
        bf16 h2 = __float2bfloat16(r2), h3 = __float2bfloat16(r3);
        ushort4 o;
        o.x = *(unsigned short*)&h0; o.y = *(unsigned short*)&h1;
        o.z = *(unsigned short*)&h2; o.w = *(unsigned short*)&h3;
        *(ushort4*)((unsigned short*)out + o4) = o;
    } else {
        *(float4*)((float*)out + o4) = make_float4(r0, r1, r2, r3);
    }
}

extern "C" void kernel_launch(void* const* d_in, const int* in_sizes, int n_in,
                              void* d_out, int out_size, void* d_ws, size_t ws_size,
                              hipStream_t stream){
    const void* x      = d_in[0];
    const void* conv_w = d_in[1];
    const void* conv_b = d_in[2];

    char* ws   = (char*)d_ws;
    int*  flag = (int*)ws;                               // 4 B
    bf16* Z    = (bf16*)(ws + 16384);                    // 256*20480 bf16 = 10,485,760 B
    float* P   = (float*)(ws + 10502144);                // 8*256*4096 fp32 = 33,554,432 B

    detect_kernel<<<1, 64, 0, stream>>>((const unsigned short*)x, flag);
    zw_kernel<<<256, 512, 0, stream>>>(x, Z, flag);
    gemm_kernel<<<256, 512, 0, stream>>>(conv_w, Z, P, flag);
    reduce_kernel<<<1024, 256, 0, stream>>>(P, conv_b, d_out, flag);
}

// Round 3
// 514.341 us; speedup vs baseline: 1.0512x; 1.0165x over previous
//
#include <hip/hip_runtime.h>
#include <hip/hip_bf16.h>

typedef __hip_bfloat16 bf16;
typedef __attribute__((ext_vector_type(8))) __bf16 bf16x8;
typedef __attribute__((ext_vector_type(4))) float f32x4;

typedef const __attribute__((address_space(1))) void cgvoid;
typedef __attribute__((address_space(3))) void lvoid;

constexpr int B_ = 256, S_ = 10, D_ = 4096, W_ = 5;
constexpr int K_ = D_ * W_;       // 20480
constexpr int M_ = 256, N_ = 4096;
constexpr int KS_ = 16;           // split-K factor -> grid 512 = 2 blocks/CU
constexpr int KPER = K_ / KS_;    // 1280
constexpr int BK_ = 32;
constexpr int ITERS = KPER / BK_; // 40
constexpr float EPSV = 1e-8f;

// ---------------- dtype detection (1 block, ~3us insurance) ----------------
__global__ void detect_kernel(const unsigned short* __restrict__ xr, int* __restrict__ flag){
    int lane = threadIdx.x;
    int sane = 0;
    for (int i = lane; i < 2048; i += 64){
        unsigned short u = xr[i];
        int e = (u >> 7) & 0xFF;
        if ((e >= 97 && e <= 137) || ((u & 0x7FFF) == 0)) sane++;
    }
    #pragma unroll
    for (int off = 32; off > 0; off >>= 1) sane += __shfl_down(sane, off);
    if (lane == 0) *flag = (sane >= 1536) ? 1 : 0;
}

// ---------------- fused cosine-weights + Z build ----------------
// One block per batch b. 512 threads x 8 i's each; x held in registers,
// block-reduce dots/norms, then windowed sums -> Z (bf16).
// Z[b, i*5+k] = sum_{t=0..5} x[b,t+k,i] * w[b,t+k]
__global__ __launch_bounds__(512) void zw_kernel(const void* __restrict__ xv,
                                                 bf16* __restrict__ Z,
                                                 const int* __restrict__ flag){
    const bool isb = (*flag != 0);
    int b = blockIdx.x, t = threadIdx.x;
    int i0 = t * 8;
    float f[S_][8];
    if (isb){
        const __bf16* xb = (const __bf16*)xv + (size_t)b * S_ * D_ + i0;
        #pragma unroll
        for (int s = 0; s < S_; ++s){
            bf16x8 v = *(const bf16x8*)(xb + s * D_);
            #pragma unroll
            for (int j = 0; j < 8; ++j) f[s][j] = (float)v[j];
        }
    } else {
        const float* xb = (const float*)xv + (size_t)b * S_ * D_ + i0;
        #pragma unroll
        for (int s = 0; s < S_; ++s){
            float4 a = *(const float4*)(xb + s * D_);
            float4 c = *(const float4*)(xb + s * D_ + 4);
            f[s][0]=a.x; f[s][1]=a.y; f[s][2]=a.z; f[s][3]=a.w;
            f[s][4]=c.x; f[s][5]=c.y; f[s][6]=c.z; f[s][7]=c.w;
        }
    }
    float dsum[S_], nsum[S_];
    #pragma unroll
    for (int s = 0; s < S_; ++s){
        float d = 0.f, n = 0.f;
        #pragma unroll
        for (int j = 0; j < 8; ++j){ d += f[s][j] * f[6][j]; n += f[s][j] * f[s][j]; }
        dsum[s] = d; nsum[s] = n;
    }
    int lane = t & 63, wv = t >> 6;
    #pragma unroll
    for (int s = 0; s < S_; ++s){
        #pragma unroll
        for (int off = 32; off > 0; off >>= 1){
            dsum[s] += __shfl_down(dsum[s], off);
            nsum[s] += __shfl_down(nsum[s], off);
        }
    }
    __shared__ float sd[8][S_], sn[8][S_], wsh[S_];
    if (lane == 0){
        #pragma unroll
        for (int s = 0; s < S_; ++s){ sd[wv][s] = dsum[s]; sn[wv][s] = nsum[s]; }
    }
    __syncthreads();
    if (t < S_){
        float Dv = 0.f, Nv = 0.f;
        #pragma unroll
        for (int w2 = 0; w2 < 8; ++w2){ Dv += sd[w2][t]; Nv += sn[w2][t]; }
        sd[0][t] = Dv; sn[0][t] = sqrtf(Nv);
    }
    __syncthreads();
    if (t < S_){
        wsh[t] = sd[0][t] / (fmaxf(sn[0][t], EPSV) * fmaxf(sn[0][6], EPSV));
    }
    __syncthreads();
    float w_[S_];
    #pragma unroll
    for (int s = 0; s < S_; ++s) w_[s] = wsh[s];
    alignas(16) __bf16 zout[40];
    #pragma unroll
    for (int k = 0; k < W_; ++k){
        #pragma unroll
        for (int j = 0; j < 8; ++j){
            float acc = 0.f;
            #pragma unroll
            for (int t2 = 0; t2 < 6; ++t2) acc += w_[k + t2] * f[k + t2][j];
            zout[j * 5 + k] = (__bf16)acc;
        }
    }
    __bf16* zp = (__bf16*)Z + (size_t)b * K_ + (size_t)i0 * W_;   // 80B/thread, contiguous
    #pragma unroll
    for (int v = 0; v < 5; ++v) *(bf16x8*)(zp + v * 8) = *(const bf16x8*)(zout + v * 8);
}

// ---------------- GEMM: P[ks] = Z(256 x K-slice) * conv_w^T(128 cols) ----------------
// Tile M=256(full) x N=128 x BK=32. 512 threads = 8 waves (4M x 2N).
// grid = 32 ntiles x 16 ks = 512 blocks = 2/CU for cross-block latency hiding.
// conv_w read exactly once across the grid; Z re-reads come from LLC.
__global__ __launch_bounds__(512, 2) void gemm_kernel(const void* __restrict__ Wv,
                                                      const bf16* __restrict__ A,
                                                      float* __restrict__ P,
                                                      const int* __restrict__ flag){
    __shared__ alignas(16) __bf16 As[256 * BK_];   // 16KB
    __shared__ alignas(16) __bf16 Bs[128 * BK_];   //  8KB
    const bool isb = (*flag != 0);
    int tid = threadIdx.x, bid = blockIdx.x;
    int nt = bid & 31, ks = bid >> 5;
    int lane = tid & 63, wv = tid >> 6;
    int wm = wv & 3, wn = wv >> 2;
    int r16 = lane & 15, quad = lane >> 4;

    const __bf16* Ab = (const __bf16*)A + (size_t)ks * KPER;

    f32x4 acc[4][4];
    #pragma unroll
    for (int fm = 0; fm < 4; ++fm)
        #pragma unroll
        for (int fn = 0; fn < 4; ++fn) acc[fm][fn] = (f32x4){0.f, 0.f, 0.f, 0.f};

    for (int kk = 0; kk < ITERS; ++kk){
        int k0 = kk * BK_;
        __syncthreads();
        #pragma unroll
        for (int r = 0; r < 2; ++r){
            int c = r * 512 + tid;                      // 1024 x 16B = 256 rows x 32
            const __bf16* src = Ab + (size_t)(c >> 2) * K_ + (c & 3) * 8 + k0;
            __builtin_amdgcn_global_load_lds((cgvoid*)src, (lvoid*)(As + c * 8), 16, 0, 0);
        }
        if (isb){
            const __bf16* Bb = (const __bf16*)Wv + (size_t)(nt * 128) * K_ + (size_t)ks * KPER;
            const __bf16* src = Bb + (size_t)(tid >> 2) * K_ + (tid & 3) * 8 + k0;
            __builtin_amdgcn_global_load_lds((cgvoid*)src, (lvoid*)(Bs + tid * 8), 16, 0, 0);
        } else {
            const float* Bb = (const float*)Wv + (size_t)(nt * 128) * K_ + (size_t)ks * KPER;
            const float* src = Bb + (size_t)(tid >> 2) * K_ + (tid & 3) * 8 + k0;
            float4 f0 = *(const float4*)src;
            float4 f1 = *(const float4*)(src + 4);
            bf16x8 u;
            u[0] = (__bf16)f0.x; u[1] = (__bf16)f0.y; u[2] = (__bf16)f0.z; u[3] = (__bf16)f0.w;
            u[4] = (__bf16)f1.x; u[5] = (__bf16)f1.y; u[6] = (__bf16)f1.z; u[7] = (__bf16)f1.w;
            *(bf16x8*)(Bs + (tid >> 2) * BK_ + (tid & 3) * 8) = u;
        }
        __syncthreads();
        bf16x8 af[4], bfr[4];
        #pragma unroll
        for (int fm = 0; fm < 4; ++fm)
            af[fm] = *(const bf16x8*)(As + (wm * 64 + fm * 16 + r16) * BK_ + quad * 8);
        #pragma unroll
        for (int fn = 0; fn < 4; ++fn)
            bfr[fn] = *(const bf16x8*)(Bs + (wn * 64 + fn * 16 + r16) * BK_ + quad * 8);
        #pragma unroll
        for (int fm = 0; fm < 4; ++fm)
            #pragma unroll
            for (int fn = 0; fn < 4; ++fn)
                acc[fm][fn] = __builtin_amdgcn_mfma_f32_16x16x32_bf16(af[fm], bfr[fn], acc[fm][fn], 0, 0, 0);
    }

    // C/D layout: col = lane&15 (N), row = quad*4 + reg (M)
    float* Pb = P + (size_t)ks * M_ * N_;
    #pragma unroll
    for (int fm = 0; fm < 4; ++fm){
        #pragma unroll
        for (int fn = 0; fn < 4; ++fn){
            int n = nt * 128 + wn * 64 + fn * 16 + r16;
            #pragma unroll
            for (int r = 0; r < 4; ++r){
                int m = wm * 64 + fm * 16 + quad * 4 + r;
                Pb[(size_t)m * N_ + n] = acc[fm][fn][r];
            }
        }
    }
}

// ---------------- split-K reduce + bias + mean scale ----------------
__global__ __launch_bounds__(256) void reduce_kernel(const float* __restrict__ P,
                                                     const void* __restrict__ bias,
                                                     void* __restrict__ out,
                                                     const int* __restrict__ flag){
    const bool isb = (*flag != 0);
    int gid = blockIdx.x * 256 + threadIdx.x;   // 262144 float4 groups
    int o4 = gid * 4;
    int n = o4 & (N_ - 1);
    float4 s = make_float4(0.f, 0.f, 0.f, 0.f);
    #pragma unroll
    for (int k2 = 0; k2 < KS_; ++k2){
        float4 p = *(const float4*)(P + (size_t)k2 * M_ * N_ + o4);
        s.x += p.x; s.y += p.y; s.z += p.z; s.w += p.w;
    }
    const float inv6 = 1.f / 6.f;
    float b0, b1, b2, b3;
    if (isb){
        const bf16* bp = (const bf16*)bias + n;
        b0 = __bfloat162float(bp[0]); b1 = __bfloat162float(bp[1]);
        b2 = __bfloat162float(bp[2]); b3 = __bfloat162float(bp[3]);
    } else {
        const float* bp = (const float*)bias + n;
        b0 = bp[0]; b1 = bp[1]; b2 = bp[2]; b3 = bp[3];
    }
    float r0 = s.x * inv6 + b0;
    float r1 = s.y * inv6 + b1;
    float r2 = s.z * inv6 + b2;
    float r3 = s.w * inv6 + b3;
    if (isb){
        bf16 h0 = __float2bfloat16(r0), h1 = __float2bfloat16(r1);
        bf16 h2 = __float2bfloat16(r2), h3 = __float2bfloat16(r3);
        ushort4 o;
        o.x = *(unsigned short*)&h0; o.y = *(unsigned short*)&h1;
        o.z = *(unsigned short*)&h2; o.w = *(unsigned short*)&h3;
        *(ushort4*)((unsigned short*)out + o4) = o;
    } else {
        *(float4*)((float*)out + o4) = make_float4(r0, r1, r2, r3);
    }
}

extern "C" void kernel_launch(void* const* d_in, const int* in_sizes, int n_in,
                              void* d_out, int out_size, void* d_ws, size_t ws_size,
                              hipStream_t stream){
    const void* x      = d_in[0];
    const void* conv_w = d_in[1];
    const void* conv_b = d_in[2];

    char* ws   = (char*)d_ws;
    int*  flag = (int*)ws;                               // 4 B
    bf16* Z    = (bf16*)(ws + 16384);                    // 256*20480 bf16 = 10,485,760 B
    float* P   = (float*)(ws + 10502144);                // 16*256*4096 fp32 = 67,108,864 B

    detect_kernel<<<1, 64, 0, stream>>>((const unsigned short*)x, flag);
    zw_kernel<<<256, 512, 0, stream>>>(x, Z, flag);
    gemm_kernel<<<512, 512, 0, stream>>>(conv_w, Z, P, flag);
    reduce_kernel<<<1024, 256, 0, stream>>>(P, conv_b, d_out, flag);
}